// Round 16
// baseline (112.450 us; speedup 1.0000x reference)
//
#include <hip/hip_runtime.h>
#include <hip/hip_bf16.h>
#include <stdint.h>

#define S_LEN 2048
#define E_DIM 1024
#define N_HEAD 16
#define HD 64
#define WIN 512

typedef __attribute__((ext_vector_type(4))) float f32x4;
typedef __attribute__((ext_vector_type(8))) short bf16x8;
typedef __attribute__((ext_vector_type(8))) unsigned short u16x8;

__device__ __forceinline__ unsigned f2bf2(float lo, float hi) {
  __hip_bfloat162 h = __float22bfloat162_rn(make_float2(lo, hi));
  return *reinterpret_cast<unsigned*>(&h);
}
__device__ __forceinline__ unsigned short f2bf(float f) {
  __hip_bfloat16 h = __float2bfloat16(f);
  return *reinterpret_cast<unsigned short*>(&h);
}
__device__ __forceinline__ float bf2f(unsigned short u) {
  union { unsigned u; float f; } v; v.u = (unsigned)u << 16; return v.f;
}

__device__ __forceinline__ void gl2lds16(const void* g, void* l) {
  __builtin_amdgcn_global_load_lds((const __attribute__((address_space(1))) void*)g,
                                   (__attribute__((address_space(3))) void*)l, 16, 0, 0);
}

// ------------- fp32 -> bf16 bulk convert + (block 0) mask prep -------------
__global__ __launch_bounds__(256) void convert_kernel(
    const float* __restrict__ q, const float* __restrict__ k, const float* __restrict__ v,
    const float* __restrict__ wq, const float* __restrict__ wk,
    const float* __restrict__ wv, const float* __restrict__ wo,
    unsigned short* __restrict__ dst, const int* __restrict__ gm,
    unsigned char* __restrict__ kmask, unsigned char* __restrict__ bflag) {
  const size_t SE = (size_t)S_LEN * E_DIM, EE = (size_t)E_DIM * E_DIM;
  if (blockIdx.x == 0) {  // mask prep (block-uniform branch)
    __shared__ int badw;
    int tid = threadIdx.x;
    if (tid == 0) badw = 0;
    __syncthreads();
    for (int i = tid; i < S_LEN / 4; i += 256) {
      int vv = gm[i];
      if (vv != 0 && vv != 1) atomicOr(&badw, 1);
    }
    __syncthreads();
    const int bytes = badw;
    const unsigned char* gb = (const unsigned char*)gm;
    for (int i = tid; i < S_LEN; i += 256)
      kmask[i] = bytes ? (unsigned char)(gb[i] != 0) : (unsigned char)(gm[i] != 0);
    if (tid < S_LEN / 64) {
      unsigned char any = 0;
      for (int j = 0; j < 64; ++j) {
        int i = tid * 64 + j;
        any |= bytes ? (unsigned char)(gb[i] != 0) : (unsigned char)(gm[i] != 0);
      }
      bflag[tid] = any;
    }
  }
  size_t i = ((size_t)blockIdx.x * 256 + threadIdx.x) * 8;
  const float* src;
  size_t off;
  if (i < SE) { src = q; off = i; }
  else if (i < 2 * SE) { src = k; off = i - SE; }
  else if (i < 3 * SE) { src = v; off = i - 2 * SE; }
  else if (i < 3 * SE + EE) { src = wq; off = i - 3 * SE; }
  else if (i < 3 * SE + 2 * EE) { src = wk; off = i - 3 * SE - EE; }
  else if (i < 3 * SE + 3 * EE) { src = wv; off = i - 3 * SE - 2 * EE; }
  else { src = wo; off = i - 3 * SE - 3 * EE; }
  f32x4 x0 = *(const f32x4*)(src + off);
  f32x4 x1 = *(const f32x4*)(src + off + 4);
  union { u16x8 v; unsigned u[4]; } o;
  o.u[0] = f2bf2(x0[0], x0[1]); o.u[1] = f2bf2(x0[2], x0[3]);
  o.u[2] = f2bf2(x1[0], x1[1]); o.u[3] = f2bf2(x1[2], x1[3]);
  *(u16x8*)(dst + i) = o.v;
}

// ---------------- 64xBN bf16 MFMA GEMM, global_load_lds staging (R9-proven) ----------------
template <int BN, int OUTMODE>
__device__ __forceinline__ void gemm_body(const unsigned short* __restrict__ A,
                                          const unsigned short* __restrict__ B,
                                          const float* __restrict__ bias,
                                          void* __restrict__ Out_) {
  __shared__ unsigned short As[64][64];
  __shared__ unsigned short Bs[BN][64];
  constexpr int MI = (BN == 128) ? 2 : 1;
  const int tid = threadIdx.x;
  const int wid = tid >> 6, lane = tid & 63;
  const int a = lane & 15, g = lane >> 4;
  const int m0 = blockIdx.y * 64, n0 = blockIdx.x * BN;
  const int wr = (BN == 128) ? (wid >> 1) * 32 : wid * 16;
  const int wc = (BN == 128) ? (wid & 1) * 64 : 0;
  const int l8 = lane >> 3, l7 = (lane & 7) * 8;
  f32x4 acc[MI][4] = {};

  for (int k0 = 0; k0 < E_DIM; k0 += 64) {
    __syncthreads();
#pragma unroll
    for (int c = 0; c < 2; ++c) {
      const int r0 = (wid * 2 + c) * 8;
      gl2lds16(A + (size_t)(m0 + r0 + l8) * E_DIM + k0 + l7, &As[r0][0]);
    }
#pragma unroll
    for (int c = 0; c < BN / 32; ++c) {
      const int r0 = (wid * (BN / 32) + c) * 8;
      gl2lds16(B + (size_t)(n0 + r0 + l8) * E_DIM + k0 + l7, &Bs[r0][0]);
    }
    __syncthreads();
#pragma unroll
    for (int s = 0; s < 2; ++s) {
      bf16x8 af[MI], bfv[4];
#pragma unroll
      for (int i = 0; i < MI; ++i) af[i] = *(const bf16x8*)&As[wr + i * 16 + a][s * 32 + g * 8];
#pragma unroll
      for (int j = 0; j < 4; ++j) bfv[j] = *(const bf16x8*)&Bs[wc + j * 16 + a][s * 32 + g * 8];
#pragma unroll
      for (int i = 0; i < MI; ++i)
#pragma unroll
        for (int j = 0; j < 4; ++j)
          acc[i][j] = __builtin_amdgcn_mfma_f32_16x16x32_bf16(af[i], bfv[j], acc[i][j], 0, 0, 0);
    }
  }
#pragma unroll
  for (int i = 0; i < MI; ++i)
#pragma unroll
    for (int j = 0; j < 4; ++j) {
      const int row0 = m0 + wr + i * 16 + g * 4;
      const int col = n0 + wc + j * 16 + a;
      if (OUTMODE == 2) {
        unsigned short* O = (unsigned short*)Out_;  // [H][HD][S] == [col][row]
        unsigned lo = f2bf2(acc[i][j][0] + bias[col], acc[i][j][1] + bias[col]);
        unsigned hi = f2bf2(acc[i][j][2] + bias[col], acc[i][j][3] + bias[col]);
        uint2 pk; pk.x = lo; pk.y = hi;
        *(uint2*)&O[(size_t)col * S_LEN + row0] = pk;
      } else {
#pragma unroll
        for (int r = 0; r < 4; ++r) {
          float v = acc[i][j][r] + bias[col];
          if (OUTMODE == 0) {
            unsigned short* O = (unsigned short*)Out_;
            O[((size_t)(col >> 6) * S_LEN + row0 + r) * HD + (col & 63)] = f2bf(v);
          } else {
            float* O = (float*)Out_;
            O[(size_t)(row0 + r) * E_DIM + col] = v;
          }
        }
      }
    }
}

__global__ __launch_bounds__(256) void gemm_qkv_kernel(
    const unsigned short* __restrict__ wsbf, const float* __restrict__ bq,
    const float* __restrict__ bk, const float* __restrict__ bv,
    unsigned short* __restrict__ Qo, unsigned short* __restrict__ Ko,
    unsigned short* __restrict__ Vo) {
  const size_t SE = (size_t)S_LEN * E_DIM, EE = (size_t)E_DIM * E_DIM;
  const int z = blockIdx.z;
  const unsigned short* A = wsbf + (size_t)z * SE;
  const unsigned short* W = wsbf + 3 * SE + (size_t)z * EE;
  const float* b = z == 0 ? bq : (z == 1 ? bk : bv);
  if (z == 2)
    gemm_body<128, 2>(A, W, b, Vo);
  else
    gemm_body<128, 0>(A, W, b, z == 0 ? Qo : Ko);
}

__global__ __launch_bounds__(256) void gemm_out_kernel(
    const unsigned short* __restrict__ Oi, const unsigned short* __restrict__ Wo,
    const float* __restrict__ bo, float* __restrict__ out) {
  gemm_body<64, 1>(Oi, Wo, bo, out);
}

// ---- attention merged: blocks x<32 = windowed rows; x>=32 = global-row key-splits ----
// windowed path: defer-max (T13) + lazy lane-partial l (single epilogue reduce)
__global__ __launch_bounds__(256) void attn_kernel(
    const unsigned short* __restrict__ Q, const unsigned short* __restrict__ K,
    const unsigned short* __restrict__ Vt_g, const unsigned char* __restrict__ kmask,
    const unsigned char* __restrict__ bflag, unsigned short* __restrict__ O,
    unsigned short* __restrict__ PA, float2* __restrict__ ML) {
  __shared__ unsigned short Kt[128][72];   // K rows [key][d], padded
  __shared__ unsigned short Vt[64][136];   // V^T rows [d][key], padded
  __shared__ float Plf[4][16][132];        // per-wave P (f32) [qrow][key]
  __shared__ unsigned char kmAll[S_LEN];

  const int tid = threadIdx.x;
  const int wid = tid >> 6, lane = tid & 63;
  const int a = lane & 15, g = lane >> 4;

  if (blockIdx.x >= 32) {
    // ===== global-query rows (0..15 of head h), one wave = one 64-key split =====
    const int h = blockIdx.y;
    const int split = (blockIdx.x - 32) * 4 + wid;  // 0..31
    const int k0 = split * 64;
    const unsigned short* Kh = K + (size_t)h * S_LEN * HD;
    const unsigned short* Vh = Vt_g + (size_t)h * HD * S_LEN;
    const float c = 0.18033688011112042f;

    const size_t qb = ((size_t)h * S_LEN + a) * HD;
    const bf16x8 qf0 = *(const bf16x8*)(Q + qb + g * 8);
    const bf16x8 qf1 = *(const bf16x8*)(Q + qb + 32 + g * 8);

    f32x4 s4[4];
#pragma unroll
    for (int t = 0; t < 4; ++t) {
      const unsigned short* kp = Kh + (size_t)(k0 + t * 16 + a) * HD;
      bf16x8 kf0 = *(const bf16x8*)(kp + g * 8);
      bf16x8 kf1 = *(const bf16x8*)(kp + 32 + g * 8);
      f32x4 z = {0.f, 0.f, 0.f, 0.f};
      z = __builtin_amdgcn_mfma_f32_16x16x32_bf16(qf0, kf0, z, 0, 0, 0);
      z = __builtin_amdgcn_mfma_f32_16x16x32_bf16(qf1, kf1, z, 0, 0, 0);
      s4[t] = z;
    }
    float m[4], l[4], tv[4][4];
#pragma unroll
    for (int t = 0; t < 4; ++t)
#pragma unroll
      for (int r = 0; r < 4; ++r) tv[t][r] = s4[t][r] * c;
#pragma unroll
    for (int r = 0; r < 4; ++r) {
      float tm = fmaxf(fmaxf(tv[0][r], tv[1][r]), fmaxf(tv[2][r], tv[3][r]));
#pragma unroll
      for (int off = 1; off < 16; off <<= 1) tm = fmaxf(tm, __shfl_xor(tm, off, 16));
      float ps = 0.f;
#pragma unroll
      for (int t = 0; t < 4; ++t) {
        float p = __builtin_amdgcn_exp2f(tv[t][r] - tm);
        tv[t][r] = p; ps += p;
      }
#pragma unroll
      for (int off = 1; off < 16; off <<= 1) ps += __shfl_xor(ps, off, 16);
      m[r] = tm; l[r] = ps;
    }
#pragma unroll
    for (int t = 0; t < 4; ++t)
#pragma unroll
      for (int r = 0; r < 4; ++r)
        Plf[wid][g * 4 + r][t * 16 + a] = tv[t][r];
    bf16x8 pa[2];
#pragma unroll
    for (int ks = 0; ks < 2; ++ks) {
      const float* pp = &Plf[wid][a][ks * 32 + g * 8];
      f32x4 x0 = *(const f32x4*)pp, x1 = *(const f32x4*)(pp + 4);
      union { bf16x8 v; unsigned u[4]; } pu;
      pu.u[0] = f2bf2(x0[0], x0[1]); pu.u[1] = f2bf2(x0[2], x0[3]);
      pu.u[2] = f2bf2(x1[0], x1[1]); pu.u[3] = f2bf2(x1[2], x1[3]);
      pa[ks] = pu.v;
    }
    f32x4 acc[4] = {};
#pragma unroll
    for (int d = 0; d < 4; ++d)
#pragma unroll
      for (int ks = 0; ks < 2; ++ks) {
        bf16x8 vf = *(const bf16x8*)(Vh + (size_t)(d * 16 + a) * S_LEN + k0 + ks * 32 + g * 8);
        acc[d] = __builtin_amdgcn_mfma_f32_16x16x32_bf16(pa[ks], vf, acc[d], 0, 0, 0);
      }
    unsigned short* pacc = PA + (((size_t)h * 32 + split) * 16) * 64;
#pragma unroll
    for (int d = 0; d < 4; ++d)
#pragma unroll
      for (int r = 0; r < 4; ++r)
        pacc[(g * 4 + r) * 64 + d * 16 + a] = f2bf(acc[d][r]);
    if (a == 0) {
      float2* pml = ML + ((size_t)h * 32 + split) * 16;
#pragma unroll
      for (int r = 0; r < 4; ++r) pml[g * 4 + r] = make_float2(m[r], l[r]);
    }
    return;
  }

  // ===== windowed rows =====
  // XCD-aware bijective remap: each XCD gets 64 consecutive logicals = 2 heads
  const int fid = blockIdx.x + (blockIdx.y << 5);
  const int logical = ((fid & 7) << 6) + (fid >> 3);
  const int h = logical >> 5;
  const int q0 = (logical & 31) << 6;
  const int qw = q0 + wid * 16;

  ((uint2*)kmAll)[tid] = ((const uint2*)kmask)[tid];

  const size_t qbase = ((size_t)h * S_LEN + (qw + a)) * HD;
  const bf16x8 qf0 = *(const bf16x8*)(Q + qbase + g * 8);
  const bf16x8 qf1 = *(const bf16x8*)(Q + qbase + 32 + g * 8);

  __syncthreads();
  int qg[4];
#pragma unroll
  for (int r = 0; r < 4; ++r) qg[r] = kmAll[qw + g * 4 + r];

  unsigned amask = 0;
  {
    int lo = (q0 - WIN) >> 7; if (lo < 0) lo = 0;
    int hi = (q0 + 63 + WIN) >> 7; if (hi > 15) hi = 15;
#pragma unroll
    for (int t2 = 0; t2 < 16; ++t2) {
      bool act = (t2 >= lo && t2 <= hi) || bflag[2 * t2] || bflag[2 * t2 + 1];
      amask |= (unsigned)act << t2;
    }
  }

  float m[4], l[4];
  f32x4 acc[4];
#pragma unroll
  for (int r = 0; r < 4; ++r) { m[r] = -1e30f; l[r] = 0.f; }
#pragma unroll
  for (int d = 0; d < 4; ++d) acc[d] = f32x4{0.f, 0.f, 0.f, 0.f};

  const unsigned short* Kh = K + (size_t)h * S_LEN * HD;
  const unsigned short* Vh = Vt_g + (size_t)h * HD * S_LEN;
  const float c = 0.18033688011112042f;  // log2(e)/8

  u16x8 kreg[4], vreg[4];
  auto issue = [&](int k0) {
    const u16x8* pk = (const u16x8*)(Kh + (size_t)(k0 + (tid >> 1)) * HD + (tid & 1) * 32);
    kreg[0] = pk[0]; kreg[1] = pk[1]; kreg[2] = pk[2]; kreg[3] = pk[3];
    const u16x8* pv = (const u16x8*)(Vh + (size_t)(tid >> 2) * S_LEN + k0 + (tid & 3) * 32);
    vreg[0] = pv[0]; vreg[1] = pv[1]; vreg[2] = pv[2]; vreg[3] = pv[3];
  };

  int kb = amask ? __builtin_ctz(amask) : 16;
  if (kb < 16) issue(kb * 128);
  while (kb < 16) {
    const unsigned rem = amask >> (kb + 1);
    const int nxt = rem ? kb + 1 + __builtin_ctz(rem) : 16;
    const int k0 = kb * 128;

    __syncthreads();
    {
      u16x8* dk = (u16x8*)&Kt[tid >> 1][(tid & 1) * 32];
      dk[0] = kreg[0]; dk[1] = kreg[1]; dk[2] = kreg[2]; dk[3] = kreg[3];
      u16x8* dv = (u16x8*)&Vt[tid >> 2][(tid & 3) * 32];
      dv[0] = vreg[0]; dv[1] = vreg[1]; dv[2] = vreg[2]; dv[3] = vreg[3];
    }
    __syncthreads();
    if (nxt < 16) issue(nxt * 128);

    // ---- QK^T ----
    f32x4 s4[8];
    __builtin_amdgcn_s_setprio(1);
#pragma unroll
    for (int t = 0; t < 8; ++t) {
      bf16x8 kf0 = *(const bf16x8*)&Kt[t * 16 + a][g * 8];
      bf16x8 kf1 = *(const bf16x8*)&Kt[t * 16 + a][32 + g * 8];
      f32x4 z = {0.f, 0.f, 0.f, 0.f};
      z = __builtin_amdgcn_mfma_f32_16x16x32_bf16(qf0, kf0, z, 0, 0, 0);
      z = __builtin_amdgcn_mfma_f32_16x16x32_bf16(qf1, kf1, z, 0, 0, 0);
      s4[t] = z;
    }
    __builtin_amdgcn_s_setprio(0);

    // ---- mask -> logits ----
    float tv[8][4];
    const bool interior = (k0 >= q0 - 449) && (k0 <= q0 + 385);
    if (interior) {
#pragma unroll
      for (int t = 0; t < 8; ++t)
#pragma unroll
        for (int r = 0; r < 4; ++r) tv[t][r] = s4[t][r] * c;
    } else {
#pragma unroll
      for (int t = 0; t < 8; ++t) {
        const int kc = k0 + t * 16 + a;
        const int kglob = kmAll[kc];
#pragma unroll
        for (int r = 0; r < 4; ++r) {
          const int qr = qw + g * 4 + r;
          bool inc = qg[r] || kglob || ((unsigned)(qr - kc + WIN) <= (unsigned)(2 * WIN));
          tv[t][r] = inc ? s4[t][r] * c : -3.0e38f;
        }
      }
    }

    // ---- defer-max softmax: lane-local partial max + wave-uniform refresh ----
    float pmax[4];
#pragma unroll
    for (int r = 0; r < 4; ++r) {
      float tm = fmaxf(fmaxf(tv[0][r], tv[1][r]), fmaxf(tv[2][r], tv[3][r]));
      tm = fmaxf(tm, fmaxf(fmaxf(tv[4][r], tv[5][r]), fmaxf(tv[6][r], tv[7][r])));
      pmax[r] = tm;
    }
    const int ok = __all((pmax[0] - m[0] <= 8.f) && (pmax[1] - m[1] <= 8.f) &&
                         (pmax[2] - m[2] <= 8.f) && (pmax[3] - m[3] <= 8.f));
    if (!ok) {  // rare: full 16-lane reduce + rescale (wave-uniform branch)
#pragma unroll
      for (int r = 0; r < 4; ++r) {
        float tm = pmax[r];
#pragma unroll
        for (int off = 1; off < 16; off <<= 1) tm = fmaxf(tm, __shfl_xor(tm, off, 16));
        const float mn = fmaxf(m[r], tm);
        const float rs = __builtin_amdgcn_exp2f(m[r] - mn);
        m[r] = mn;
        l[r] *= rs;
#pragma unroll
        for (int d = 0; d < 4; ++d) acc[d][r] *= rs;
      }
    }
#pragma unroll
    for (int r = 0; r < 4; ++r) {  // lazy-l: lane-partial sum only
      float ps = 0.f;
#pragma unroll
      for (int t = 0; t < 8; ++t) {
        float p = __builtin_amdgcn_exp2f(tv[t][r] - m[r]);
        tv[t][r] = p; ps += p;
      }
      l[r] += ps;
    }

    // ---- P transpose via wave-private f32 LDS ----
#pragma unroll
    for (int t = 0; t < 8; ++t)
#pragma unroll
      for (int r = 0; r < 4; ++r)
        Plf[wid][g * 4 + r][t * 16 + a] = tv[t][r];
    bf16x8 pa[4];
#pragma unroll
    for (int ks = 0; ks < 4; ++ks) {
      const float* pp = &Plf[wid][a][ks * 32 + g * 8];
      f32x4 x0 = *(const f32x4*)pp, x1 = *(const f32x4*)(pp + 4);
      union { bf16x8 v; unsigned u[4]; } pu;
      pu.u[0] = f2bf2(x0[0], x0[1]); pu.u[1] = f2bf2(x0[2], x0[3]);
      pu.u[2] = f2bf2(x1[0], x1[1]); pu.u[3] = f2bf2(x1[2], x1[3]);
      pa[ks] = pu.v;
    }

    // ---- PV ----
    __builtin_amdgcn_s_setprio(1);
#pragma unroll
    for (int d = 0; d < 4; ++d)
#pragma unroll
      for (int ks = 0; ks < 4; ++ks) {
        bf16x8 vf = *(const bf16x8*)&Vt[d * 16 + a][ks * 32 + g * 8];
        acc[d] = __builtin_amdgcn_mfma_f32_16x16x32_bf16(pa[ks], vf, acc[d], 0, 0, 0);
      }
    __builtin_amdgcn_s_setprio(0);
    kb = nxt;
  }

  // epilogue: single l-reduce across the 16 a-lanes, then normalize
#pragma unroll
  for (int r = 0; r < 4; ++r) {
#pragma unroll
    for (int off = 1; off < 16; off <<= 1) l[r] += __shfl_xor(l[r], off, 16);
  }
#pragma unroll
  for (int d = 0; d < 4; ++d)
#pragma unroll
    for (int r = 0; r < 4; ++r) {
      const int qr = qw + g * 4 + r;
      float v = acc[d][r] / l[r];
      O[(size_t)qr * E_DIM + h * HD + d * 16 + a] = f2bf(v);
    }
}

// ---- combine 32 key-split partials for the 16 global rows per head ----
__global__ __launch_bounds__(256) void combine_glb_kernel(
    const unsigned short* __restrict__ PA, const float2* __restrict__ ML,
    unsigned short* __restrict__ O) {
  const int h = blockIdx.x, tid = threadIdx.x;
  const int row = tid >> 4, d0 = (tid & 15) * 4;  // 16 rows x 64 d
  float M = -1e30f;
#pragma unroll 8
  for (int s = 0; s < 32; ++s) M = fmaxf(M, ML[((size_t)h * 32 + s) * 16 + row].x);
  float L = 0.f, o0 = 0.f, o1 = 0.f, o2 = 0.f, o3 = 0.f;
  for (int s = 0; s < 32; ++s) {
    float2 ml = ML[((size_t)h * 32 + s) * 16 + row];
    float w = __builtin_amdgcn_exp2f(ml.x - M);
    L += w * ml.y;
    const unsigned short* p = PA + (((size_t)h * 32 + s) * 16 + row) * 64 + d0;
    o0 += w * bf2f(p[0]); o1 += w * bf2f(p[1]);
    o2 += w * bf2f(p[2]); o3 += w * bf2f(p[3]);
  }
  const float inv = 1.0f / L;
  uint2 pk;
  pk.x = f2bf2(o0 * inv, o1 * inv);
  pk.y = f2bf2(o2 * inv, o3 * inv);
  *(uint2*)&O[(size_t)row * E_DIM + h * HD + d0] = pk;
}

extern "C" void kernel_launch(void* const* d_in, const int* in_sizes, int n_in,
                              void* d_out, int out_size, void* d_ws, size_t ws_size,
                              hipStream_t stream) {
  const float* q  = (const float*)d_in[0];
  const float* k  = (const float*)d_in[1];
  const float* v  = (const float*)d_in[2];
  const int* isg  = (const int*)d_in[3];
  const float* Wq = (const float*)d_in[4];
  const float* bq = (const float*)d_in[5];
  const float* Wk = (const float*)d_in[6];
  const float* bk = (const float*)d_in[7];
  const float* Wv = (const float*)d_in[8];
  const float* bv = (const float*)d_in[9];
  const float* Wo = (const float*)d_in[10];
  const float* bo = (const float*)d_in[11];

  const size_t SE = (size_t)S_LEN * E_DIM, EE = (size_t)E_DIM * E_DIM;
  unsigned short* wsbf = (unsigned short*)d_ws;   // [q|k|v|Wq|Wk|Wv|Wo] bf16
  unsigned short* Qb = wsbf + 3 * SE + 4 * EE;    // [H][S][HD]
  unsigned short* Kb = Qb + SE;                   // [H][S][HD]
  unsigned short* Vb = Kb + SE;                   // [H][HD][S] (transposed)
  unsigned short* Ob = wsbf;                      // alias q-bf16 (dead after qkv GEMM)
  unsigned char* kmask = (unsigned char*)(Vb + SE);
  unsigned char* bflag = kmask + S_LEN;
  // global-row partials alias dead k-bf16 region
  unsigned short* PA = wsbf + SE;                        // 16*32*16*64 bf16 = 1MB
  float2* ML = (float2*)(PA + (size_t)16 * 32 * 16 * 64);

  const int total_conv_blocks = (int)((3 * SE + 4 * EE) / (256 * 8));
  convert_kernel<<<total_conv_blocks, 256, 0, stream>>>(q, k, v, Wq, Wk, Wv, Wo, wsbf,
                                                        isg, kmask, bflag);
  gemm_qkv_kernel<<<dim3(E_DIM / 128, S_LEN / 64, 3), 256, 0, stream>>>(
      wsbf, bq, bk, bv, Qb, Kb, Vb);
  attn_kernel<<<dim3(40, N_HEAD), 256, 0, stream>>>(Qb, Kb, Vb, kmask, bflag, Ob, PA, ML);
  combine_glb_kernel<<<N_HEAD, 256, 0, stream>>>(PA, ML, Ob);
  gemm_out_kernel<<<dim3(E_DIM / 64, S_LEN / 64), 256, 0, stream>>>(
      Ob, wsbf + 3 * SE + 3 * EE, bo, (float*)d_out);
}

// Round 17
// 101.556 us; speedup vs baseline: 1.1073x; 1.1073x over previous
//
#include <hip/hip_runtime.h>
#include <hip/hip_bf16.h>
#include <stdint.h>

#define S_LEN 2048
#define E_DIM 1024
#define N_HEAD 16
#define HD 64
#define WIN 512

typedef __attribute__((ext_vector_type(4))) float f32x4;
typedef __attribute__((ext_vector_type(8))) short bf16x8;
typedef __attribute__((ext_vector_type(8))) unsigned short u16x8;

__device__ __forceinline__ unsigned f2bf2(float lo, float hi) {
  __hip_bfloat162 h = __float22bfloat162_rn(make_float2(lo, hi));
  return *reinterpret_cast<unsigned*>(&h);
}
__device__ __forceinline__ unsigned short f2bf(float f) {
  __hip_bfloat16 h = __float2bfloat16(f);
  return *reinterpret_cast<unsigned short*>(&h);
}
__device__ __forceinline__ float bf2f(unsigned short u) {
  union { unsigned u; float f; } v; v.u = (unsigned)u << 16; return v.f;
}

__device__ __forceinline__ void gl2lds16(const void* g, void* l) {
  __builtin_amdgcn_global_load_lds((const __attribute__((address_space(1))) void*)g,
                                   (__attribute__((address_space(3))) void*)l, 16, 0, 0);
}

// ------------- fp32 -> bf16 bulk convert + (block 0) mask prep -------------
__global__ __launch_bounds__(256) void convert_kernel(
    const float* __restrict__ q, const float* __restrict__ k, const float* __restrict__ v,
    const float* __restrict__ wq, const float* __restrict__ wk,
    const float* __restrict__ wv, const float* __restrict__ wo,
    unsigned short* __restrict__ dst, const int* __restrict__ gm,
    unsigned char* __restrict__ kmask, unsigned char* __restrict__ bflag) {
  const size_t SE = (size_t)S_LEN * E_DIM, EE = (size_t)E_DIM * E_DIM;
  if (blockIdx.x == 0) {  // mask prep (block-uniform branch)
    __shared__ int badw;
    int tid = threadIdx.x;
    if (tid == 0) badw = 0;
    __syncthreads();
    for (int i = tid; i < S_LEN / 4; i += 256) {
      int vv = gm[i];
      if (vv != 0 && vv != 1) atomicOr(&badw, 1);
    }
    __syncthreads();
    const int bytes = badw;
    const unsigned char* gb = (const unsigned char*)gm;
    for (int i = tid; i < S_LEN; i += 256)
      kmask[i] = bytes ? (unsigned char)(gb[i] != 0) : (unsigned char)(gm[i] != 0);
    if (tid < S_LEN / 64) {
      unsigned char any = 0;
      for (int j = 0; j < 64; ++j) {
        int i = tid * 64 + j;
        any |= bytes ? (unsigned char)(gb[i] != 0) : (unsigned char)(gm[i] != 0);
      }
      bflag[tid] = any;
    }
  }
  size_t i = ((size_t)blockIdx.x * 256 + threadIdx.x) * 8;
  const float* src;
  size_t off;
  if (i < SE) { src = q; off = i; }
  else if (i < 2 * SE) { src = k; off = i - SE; }
  else if (i < 3 * SE) { src = v; off = i - 2 * SE; }
  else if (i < 3 * SE + EE) { src = wq; off = i - 3 * SE; }
  else if (i < 3 * SE + 2 * EE) { src = wk; off = i - 3 * SE - EE; }
  else if (i < 3 * SE + 3 * EE) { src = wv; off = i - 3 * SE - 2 * EE; }
  else { src = wo; off = i - 3 * SE - 3 * EE; }
  f32x4 x0 = *(const f32x4*)(src + off);
  f32x4 x1 = *(const f32x4*)(src + off + 4);
  union { u16x8 v; unsigned u[4]; } o;
  o.u[0] = f2bf2(x0[0], x0[1]); o.u[1] = f2bf2(x0[2], x0[3]);
  o.u[2] = f2bf2(x1[0], x1[1]); o.u[3] = f2bf2(x1[2], x1[3]);
  *(u16x8*)(dst + i) = o.v;
}

// ---------------- 64xBN bf16 MFMA GEMM, global_load_lds staging (R9-proven) ----------------
template <int BN, int OUTMODE>
__device__ __forceinline__ void gemm_body(const unsigned short* __restrict__ A,
                                          const unsigned short* __restrict__ B,
                                          const float* __restrict__ bias,
                                          void* __restrict__ Out_) {
  __shared__ unsigned short As[64][64];
  __shared__ unsigned short Bs[BN][64];
  constexpr int MI = (BN == 128) ? 2 : 1;
  const int tid = threadIdx.x;
  const int wid = tid >> 6, lane = tid & 63;
  const int a = lane & 15, g = lane >> 4;
  const int m0 = blockIdx.y * 64, n0 = blockIdx.x * BN;
  const int wr = (BN == 128) ? (wid >> 1) * 32 : wid * 16;
  const int wc = (BN == 128) ? (wid & 1) * 64 : 0;
  const int l8 = lane >> 3, l7 = (lane & 7) * 8;
  f32x4 acc[MI][4] = {};

  for (int k0 = 0; k0 < E_DIM; k0 += 64) {
    __syncthreads();
#pragma unroll
    for (int c = 0; c < 2; ++c) {
      const int r0 = (wid * 2 + c) * 8;
      gl2lds16(A + (size_t)(m0 + r0 + l8) * E_DIM + k0 + l7, &As[r0][0]);
    }
#pragma unroll
    for (int c = 0; c < BN / 32; ++c) {
      const int r0 = (wid * (BN / 32) + c) * 8;
      gl2lds16(B + (size_t)(n0 + r0 + l8) * E_DIM + k0 + l7, &Bs[r0][0]);
    }
    __syncthreads();
#pragma unroll
    for (int s = 0; s < 2; ++s) {
      bf16x8 af[MI], bfv[4];
#pragma unroll
      for (int i = 0; i < MI; ++i) af[i] = *(const bf16x8*)&As[wr + i * 16 + a][s * 32 + g * 8];
#pragma unroll
      for (int j = 0; j < 4; ++j) bfv[j] = *(const bf16x8*)&Bs[wc + j * 16 + a][s * 32 + g * 8];
#pragma unroll
      for (int i = 0; i < MI; ++i)
#pragma unroll
        for (int j = 0; j < 4; ++j)
          acc[i][j] = __builtin_amdgcn_mfma_f32_16x16x32_bf16(af[i], bfv[j], acc[i][j], 0, 0, 0);
    }
  }
#pragma unroll
  for (int i = 0; i < MI; ++i)
#pragma unroll
    for (int j = 0; j < 4; ++j) {
      const int row0 = m0 + wr + i * 16 + g * 4;
      const int col = n0 + wc + j * 16 + a;
      if (OUTMODE == 2) {
        unsigned short* O = (unsigned short*)Out_;  // [H][HD][S] == [col][row]
        unsigned lo = f2bf2(acc[i][j][0] + bias[col], acc[i][j][1] + bias[col]);
        unsigned hi = f2bf2(acc[i][j][2] + bias[col], acc[i][j][3] + bias[col]);
        uint2 pk; pk.x = lo; pk.y = hi;
        *(uint2*)&O[(size_t)col * S_LEN + row0] = pk;
      } else {
#pragma unroll
        for (int r = 0; r < 4; ++r) {
          float v = acc[i][j][r] + bias[col];
          if (OUTMODE == 0) {
            unsigned short* O = (unsigned short*)Out_;
            O[((size_t)(col >> 6) * S_LEN + row0 + r) * HD + (col & 63)] = f2bf(v);
          } else {
            float* O = (float*)Out_;
            O[(size_t)(row0 + r) * E_DIM + col] = v;
          }
        }
      }
    }
}

__global__ __launch_bounds__(256) void gemm_qkv_kernel(
    const unsigned short* __restrict__ wsbf, const float* __restrict__ bq,
    const float* __restrict__ bk, const float* __restrict__ bv,
    unsigned short* __restrict__ Qo, unsigned short* __restrict__ Ko,
    unsigned short* __restrict__ Vo) {
  const size_t SE = (size_t)S_LEN * E_DIM, EE = (size_t)E_DIM * E_DIM;
  const int z = blockIdx.z;
  const unsigned short* A = wsbf + (size_t)z * SE;
  const unsigned short* W = wsbf + 3 * SE + (size_t)z * EE;
  const float* b = z == 0 ? bq : (z == 1 ? bk : bv);
  if (z == 2)
    gemm_body<128, 2>(A, W, b, Vo);
  else
    gemm_body<128, 0>(A, W, b, z == 0 ? Qo : Ko);
}

__global__ __launch_bounds__(256) void gemm_out_kernel(
    const unsigned short* __restrict__ Oi, const unsigned short* __restrict__ Wo,
    const float* __restrict__ bo, float* __restrict__ out) {
  gemm_body<64, 1>(Oi, Wo, bo, out);
}

// ---- attention merged: blocks x<32 = windowed rows; x==32 = fused global-row block ----
// win path: defer-max + lazy-l; skips stores for global-query rows (glb block owns them)
__global__ __launch_bounds__(256) void attn_kernel(
    const unsigned short* __restrict__ Q, const unsigned short* __restrict__ K,
    const unsigned short* __restrict__ Vt_g, const unsigned char* __restrict__ kmask,
    const unsigned char* __restrict__ bflag, unsigned short* __restrict__ O) {
  __shared__ unsigned short Kt[128][72];   // K rows [key][d], padded
  __shared__ unsigned short Vt[64][136];   // V^T rows [d][key], padded
  __shared__ float Plf[4][16][132];        // per-wave P (f32) + glb combine buffer
  __shared__ unsigned char kmAll[S_LEN];

  const int tid = threadIdx.x;
  const int wid = tid >> 6, lane = tid & 63;
  const int a = lane & 15, g = lane >> 4;

  if (blockIdx.x == 32) {
    // ===== global-query rows 0..15 of head h: each wave owns 512 keys (8 chunks),
    //       online softmax per wave, then in-block LDS combine =====
    const int h = blockIdx.y;
    const unsigned short* Kh = K + (size_t)h * S_LEN * HD;
    const unsigned short* Vh = Vt_g + (size_t)h * HD * S_LEN;
    const float c = 0.18033688011112042f;

    const size_t qb = ((size_t)h * S_LEN + a) * HD;
    const bf16x8 qf0 = *(const bf16x8*)(Q + qb + g * 8);
    const bf16x8 qf1 = *(const bf16x8*)(Q + qb + 32 + g * 8);

    float m[4], l[4];
    f32x4 acc[4];
#pragma unroll
    for (int r = 0; r < 4; ++r) { m[r] = -1e30f; l[r] = 0.f; }
#pragma unroll
    for (int d = 0; d < 4; ++d) acc[d] = f32x4{0.f, 0.f, 0.f, 0.f};

    for (int ch = 0; ch < 8; ++ch) {
      const int k0 = wid * 512 + ch * 64;
      f32x4 s4[4];
#pragma unroll
      for (int t = 0; t < 4; ++t) {
        const unsigned short* kp = Kh + (size_t)(k0 + t * 16 + a) * HD;
        bf16x8 kf0 = *(const bf16x8*)(kp + g * 8);
        bf16x8 kf1 = *(const bf16x8*)(kp + 32 + g * 8);
        f32x4 z = {0.f, 0.f, 0.f, 0.f};
        z = __builtin_amdgcn_mfma_f32_16x16x32_bf16(qf0, kf0, z, 0, 0, 0);
        z = __builtin_amdgcn_mfma_f32_16x16x32_bf16(qf1, kf1, z, 0, 0, 0);
        s4[t] = z;
      }
      float tv[4][4];
#pragma unroll
      for (int t = 0; t < 4; ++t)
#pragma unroll
        for (int r = 0; r < 4; ++r) tv[t][r] = s4[t][r] * c;
#pragma unroll
      for (int r = 0; r < 4; ++r) {
        float tm = fmaxf(fmaxf(tv[0][r], tv[1][r]), fmaxf(tv[2][r], tv[3][r]));
#pragma unroll
        for (int off = 1; off < 16; off <<= 1) tm = fmaxf(tm, __shfl_xor(tm, off, 16));
        const float mn = fmaxf(m[r], tm);
        const float rs = __builtin_amdgcn_exp2f(m[r] - mn);
        m[r] = mn;
        float ps = 0.f;
#pragma unroll
        for (int t = 0; t < 4; ++t) {
          float p = __builtin_amdgcn_exp2f(tv[t][r] - mn);
          tv[t][r] = p; ps += p;
        }
#pragma unroll
        for (int off = 1; off < 16; off <<= 1) ps += __shfl_xor(ps, off, 16);
        l[r] = l[r] * rs + ps;
#pragma unroll
        for (int d = 0; d < 4; ++d) acc[d][r] *= rs;
      }
      // P transpose via wave-private LDS slice (cols 0..63)
#pragma unroll
      for (int t = 0; t < 4; ++t)
#pragma unroll
        for (int r = 0; r < 4; ++r)
          Plf[wid][g * 4 + r][t * 16 + a] = tv[t][r];
      bf16x8 pa[2];
#pragma unroll
      for (int ks = 0; ks < 2; ++ks) {
        const float* pp = &Plf[wid][a][ks * 32 + g * 8];
        f32x4 x0 = *(const f32x4*)pp, x1 = *(const f32x4*)(pp + 4);
        union { bf16x8 v; unsigned u[4]; } pu;
        pu.u[0] = f2bf2(x0[0], x0[1]); pu.u[1] = f2bf2(x0[2], x0[3]);
        pu.u[2] = f2bf2(x1[0], x1[1]); pu.u[3] = f2bf2(x1[2], x1[3]);
        pa[ks] = pu.v;
      }
#pragma unroll
      for (int d = 0; d < 4; ++d)
#pragma unroll
        for (int ks = 0; ks < 2; ++ks) {
          bf16x8 vf = *(const bf16x8*)(Vh + (size_t)(d * 16 + a) * S_LEN + k0 + ks * 32 + g * 8);
          acc[d] = __builtin_amdgcn_mfma_f32_16x16x32_bf16(pa[ks], vf, acc[d], 0, 0, 0);
        }
    }

    // write wave partials: acc -> cols [64..127], m -> [128], l -> [129]
#pragma unroll
    for (int d = 0; d < 4; ++d)
#pragma unroll
      for (int r = 0; r < 4; ++r)
        Plf[wid][g * 4 + r][64 + d * 16 + a] = acc[d][r];
    if (a == 0) {
#pragma unroll
      for (int r = 0; r < 4; ++r) {
        Plf[wid][g * 4 + r][128] = m[r];
        Plf[wid][g * 4 + r][129] = l[r];
      }
    }
    __syncthreads();

    // combine 4 wave partials; 256 threads = 16 rows x 16 d-groups of 4
    {
      const int row = tid >> 4, d0q = (tid & 15) * 4;
      float M = Plf[0][row][128];
#pragma unroll
      for (int w = 1; w < 4; ++w) M = fmaxf(M, Plf[w][row][128]);
      float L = 0.f, o0 = 0.f, o1 = 0.f, o2 = 0.f, o3 = 0.f;
#pragma unroll
      for (int w = 0; w < 4; ++w) {
        const float wg = __builtin_amdgcn_exp2f(Plf[w][row][128] - M);
        L += wg * Plf[w][row][129];
        o0 += wg * Plf[w][row][64 + d0q];
        o1 += wg * Plf[w][row][64 + d0q + 1];
        o2 += wg * Plf[w][row][64 + d0q + 2];
        o3 += wg * Plf[w][row][64 + d0q + 3];
      }
      const float inv = 1.0f / L;
      uint2 pk;
      pk.x = f2bf2(o0 * inv, o1 * inv);
      pk.y = f2bf2(o2 * inv, o3 * inv);
      *(uint2*)&O[(size_t)row * E_DIM + h * HD + d0q] = pk;
    }
    return;
  }

  // ===== windowed rows =====
  // XCD-aware bijective remap: each XCD gets 64 consecutive logicals = 2 heads
  const int fid = blockIdx.x + (blockIdx.y << 5);
  const int logical = ((fid & 7) << 6) + (fid >> 3);
  const int h = logical >> 5;
  const int q0 = (logical & 31) << 6;
  const int qw = q0 + wid * 16;

  ((uint2*)kmAll)[tid] = ((const uint2*)kmask)[tid];

  const size_t qbase = ((size_t)h * S_LEN + (qw + a)) * HD;
  const bf16x8 qf0 = *(const bf16x8*)(Q + qbase + g * 8);
  const bf16x8 qf1 = *(const bf16x8*)(Q + qbase + 32 + g * 8);

  __syncthreads();
  int qg[4];
#pragma unroll
  for (int r = 0; r < 4; ++r) qg[r] = kmAll[qw + g * 4 + r];

  unsigned amask = 0;
  {
    int lo = (q0 - WIN) >> 7; if (lo < 0) lo = 0;
    int hi = (q0 + 63 + WIN) >> 7; if (hi > 15) hi = 15;
#pragma unroll
    for (int t2 = 0; t2 < 16; ++t2) {
      bool act = (t2 >= lo && t2 <= hi) || bflag[2 * t2] || bflag[2 * t2 + 1];
      amask |= (unsigned)act << t2;
    }
  }

  float m[4], l[4];
  f32x4 acc[4];
#pragma unroll
  for (int r = 0; r < 4; ++r) { m[r] = -1e30f; l[r] = 0.f; }
#pragma unroll
  for (int d = 0; d < 4; ++d) acc[d] = f32x4{0.f, 0.f, 0.f, 0.f};

  const unsigned short* Kh = K + (size_t)h * S_LEN * HD;
  const unsigned short* Vh = Vt_g + (size_t)h * HD * S_LEN;
  const float c = 0.18033688011112042f;  // log2(e)/8

  u16x8 kreg[4], vreg[4];
  auto issue = [&](int k0) {
    const u16x8* pk = (const u16x8*)(Kh + (size_t)(k0 + (tid >> 1)) * HD + (tid & 1) * 32);
    kreg[0] = pk[0]; kreg[1] = pk[1]; kreg[2] = pk[2]; kreg[3] = pk[3];
    const u16x8* pv = (const u16x8*)(Vh + (size_t)(tid >> 2) * S_LEN + k0 + (tid & 3) * 32);
    vreg[0] = pv[0]; vreg[1] = pv[1]; vreg[2] = pv[2]; vreg[3] = pv[3];
  };

  int kb = amask ? __builtin_ctz(amask) : 16;
  if (kb < 16) issue(kb * 128);
  while (kb < 16) {
    const unsigned rem = amask >> (kb + 1);
    const int nxt = rem ? kb + 1 + __builtin_ctz(rem) : 16;
    const int k0 = kb * 128;

    __syncthreads();
    {
      u16x8* dk = (u16x8*)&Kt[tid >> 1][(tid & 1) * 32];
      dk[0] = kreg[0]; dk[1] = kreg[1]; dk[2] = kreg[2]; dk[3] = kreg[3];
      u16x8* dv = (u16x8*)&Vt[tid >> 2][(tid & 3) * 32];
      dv[0] = vreg[0]; dv[1] = vreg[1]; dv[2] = vreg[2]; dv[3] = vreg[3];
    }
    __syncthreads();
    if (nxt < 16) issue(nxt * 128);

    // ---- QK^T ----
    f32x4 s4[8];
    __builtin_amdgcn_s_setprio(1);
#pragma unroll
    for (int t = 0; t < 8; ++t) {
      bf16x8 kf0 = *(const bf16x8*)&Kt[t * 16 + a][g * 8];
      bf16x8 kf1 = *(const bf16x8*)&Kt[t * 16 + a][32 + g * 8];
      f32x4 z = {0.f, 0.f, 0.f, 0.f};
      z = __builtin_amdgcn_mfma_f32_16x16x32_bf16(qf0, kf0, z, 0, 0, 0);
      z = __builtin_amdgcn_mfma_f32_16x16x32_bf16(qf1, kf1, z, 0, 0, 0);
      s4[t] = z;
    }
    __builtin_amdgcn_s_setprio(0);

    // ---- mask -> logits ----
    float tv[8][4];
    const bool interior = (k0 >= q0 - 449) && (k0 <= q0 + 385);
    if (interior) {
#pragma unroll
      for (int t = 0; t < 8; ++t)
#pragma unroll
        for (int r = 0; r < 4; ++r) tv[t][r] = s4[t][r] * c;
    } else {
#pragma unroll
      for (int t = 0; t < 8; ++t) {
        const int kc = k0 + t * 16 + a;
        const int kglob = kmAll[kc];
#pragma unroll
        for (int r = 0; r < 4; ++r) {
          const int qr = qw + g * 4 + r;
          bool inc = qg[r] || kglob || ((unsigned)(qr - kc + WIN) <= (unsigned)(2 * WIN));
          tv[t][r] = inc ? s4[t][r] * c : -3.0e38f;
        }
      }
    }

    // ---- defer-max softmax: lane-local partial max + wave-uniform refresh ----
    float pmax[4];
#pragma unroll
    for (int r = 0; r < 4; ++r) {
      float tm = fmaxf(fmaxf(tv[0][r], tv[1][r]), fmaxf(tv[2][r], tv[3][r]));
      tm = fmaxf(tm, fmaxf(fmaxf(tv[4][r], tv[5][r]), fmaxf(tv[6][r], tv[7][r])));
      pmax[r] = tm;
    }
    const int ok = __all((pmax[0] - m[0] <= 8.f) && (pmax[1] - m[1] <= 8.f) &&
                         (pmax[2] - m[2] <= 8.f) && (pmax[3] - m[3] <= 8.f));
    if (!ok) {  // rare: full 16-lane reduce + rescale (wave-uniform branch)
#pragma unroll
      for (int r = 0; r < 4; ++r) {
        float tm = pmax[r];
#pragma unroll
        for (int off = 1; off < 16; off <<= 1) tm = fmaxf(tm, __shfl_xor(tm, off, 16));
        const float mn = fmaxf(m[r], tm);
        const float rs = __builtin_amdgcn_exp2f(m[r] - mn);
        m[r] = mn;
        l[r] *= rs;
#pragma unroll
        for (int d = 0; d < 4; ++d) acc[d][r] *= rs;
      }
    }
#pragma unroll
    for (int r = 0; r < 4; ++r) {  // lazy-l: lane-partial sum only
      float ps = 0.f;
#pragma unroll
      for (int t = 0; t < 8; ++t) {
        float p = __builtin_amdgcn_exp2f(tv[t][r] - m[r]);
        tv[t][r] = p; ps += p;
      }
      l[r] += ps;
    }

    // ---- P transpose via wave-private f32 LDS ----
#pragma unroll
    for (int t = 0; t < 8; ++t)
#pragma unroll
      for (int r = 0; r < 4; ++r)
        Plf[wid][g * 4 + r][t * 16 + a] = tv[t][r];
    bf16x8 pa[4];
#pragma unroll
    for (int ks = 0; ks < 4; ++ks) {
      const float* pp = &Plf[wid][a][ks * 32 + g * 8];
      f32x4 x0 = *(const f32x4*)pp, x1 = *(const f32x4*)(pp + 4);
      union { bf16x8 v; unsigned u[4]; } pu;
      pu.u[0] = f2bf2(x0[0], x0[1]); pu.u[1] = f2bf2(x0[2], x0[3]);
      pu.u[2] = f2bf2(x1[0], x1[1]); pu.u[3] = f2bf2(x1[2], x1[3]);
      pa[ks] = pu.v;
    }

    // ---- PV ----
    __builtin_amdgcn_s_setprio(1);
#pragma unroll
    for (int d = 0; d < 4; ++d)
#pragma unroll
      for (int ks = 0; ks < 4; ++ks) {
        bf16x8 vf = *(const bf16x8*)&Vt[d * 16 + a][ks * 32 + g * 8];
        acc[d] = __builtin_amdgcn_mfma_f32_16x16x32_bf16(pa[ks], vf, acc[d], 0, 0, 0);
      }
    __builtin_amdgcn_s_setprio(0);
    kb = nxt;
  }

  // epilogue: single l-reduce; skip global-query rows (fused glb block owns them)
#pragma unroll
  for (int r = 0; r < 4; ++r) {
#pragma unroll
    for (int off = 1; off < 16; off <<= 1) l[r] += __shfl_xor(l[r], off, 16);
  }
#pragma unroll
  for (int d = 0; d < 4; ++d)
#pragma unroll
    for (int r = 0; r < 4; ++r) {
      if (qg[r]) continue;  // global-query row: written by the x==32 block
      const int qr = qw + g * 4 + r;
      float v = acc[d][r] / l[r];
      O[(size_t)qr * E_DIM + h * HD + d * 16 + a] = f2bf(v);
    }
}

extern "C" void kernel_launch(void* const* d_in, const int* in_sizes, int n_in,
                              void* d_out, int out_size, void* d_ws, size_t ws_size,
                              hipStream_t stream) {
  const float* q  = (const float*)d_in[0];
  const float* k  = (const float*)d_in[1];
  const float* v  = (const float*)d_in[2];
  const int* isg  = (const int*)d_in[3];
  const float* Wq = (const float*)d_in[4];
  const float* bq = (const float*)d_in[5];
  const float* Wk = (const float*)d_in[6];
  const float* bk = (const float*)d_in[7];
  const float* Wv = (const float*)d_in[8];
  const float* bv = (const float*)d_in[9];
  const float* Wo = (const float*)d_in[10];
  const float* bo = (const float*)d_in[11];

  const size_t SE = (size_t)S_LEN * E_DIM, EE = (size_t)E_DIM * E_DIM;
  unsigned short* wsbf = (unsigned short*)d_ws;   // [q|k|v|Wq|Wk|Wv|Wo] bf16
  unsigned short* Qb = wsbf + 3 * SE + 4 * EE;    // [H][S][HD]
  unsigned short* Kb = Qb + SE;                   // [H][S][HD]
  unsigned short* Vb = Kb + SE;                   // [H][HD][S] (transposed)
  unsigned short* Ob = wsbf;                      // alias q-bf16 (dead after qkv GEMM)
  unsigned char* kmask = (unsigned char*)(Vb + SE);
  unsigned char* bflag = kmask + S_LEN;

  const int total_conv_blocks = (int)((3 * SE + 4 * EE) / (256 * 8));
  convert_kernel<<<total_conv_blocks, 256, 0, stream>>>(q, k, v, Wq, Wk, Wv, Wo, wsbf,
                                                        isg, kmask, bflag);
  gemm_qkv_kernel<<<dim3(E_DIM / 128, S_LEN / 64, 3), 256, 0, stream>>>(
      wsbf, bq, bk, bv, Qb, Kb, Vb);
  attn_kernel<<<dim3(33, N_HEAD), 256, 0, stream>>>(Qb, Kb, Vb, kmask, bflag, Ob);
  gemm_out_kernel<<<dim3(E_DIM / 64, S_LEN / 64), 256, 0, stream>>>(
      Ob, wsbf + 3 * SE + 3 * EE, bo, (float*)d_out);
}